// Round 12
// baseline (203.046 us; speedup 1.0000x reference)
//
#include <hip/hip_runtime.h>

#define NUM_EMB 1024
#define EMB_DIM 256

typedef __attribute__((ext_vector_type(8))) short short8v;
typedef __attribute__((ext_vector_type(4))) float f32x4;
typedef unsigned long long u64;
typedef unsigned int u32;

__device__ __forceinline__ u32 sortable(float f) {
    u32 u = __float_as_uint(f);
    return (u & 0x80000000u) ? ~u : (u | 0x80000000u);
}
__device__ __forceinline__ float unsortable(u32 s) {
    u32 u = (s & 0x80000000u) ? (s & 0x7FFFFFFFu) : ~s;
    return __uint_as_float(u);
}
__device__ __forceinline__ u64 umin64(u64 a, u64 b) { return a < b ? a : b; }

// RNE fp32 -> bf16 bits
__device__ __forceinline__ unsigned short f2bf(float f) {
    u32 u = __float_as_uint(f);
    u32 r = (u + 0x7FFFu + ((u >> 16) & 1u)) >> 16;
    return (unsigned short)r;
}
__device__ __forceinline__ float bf2f(unsigned short h) {
    return __uint_as_float(((u32)h) << 16);
}

#define GLP(p)  ((const __attribute__((address_space(1))) unsigned int*)(p))
#define LDSP(p) ((__attribute__((address_space(3))) unsigned int*)(p))

// ---- fused prep: role-split by blockIdx ----
// bid 0..63: transpose E->ET; 64..65: normE + maxE; 66..97: eprep (Eh ks0-3, El ks4-7)
// bid 98..353: xprep -> Xs hi-panel only ([mblk128 of 256 rows][ks 0..3][32KB]), + per-row ||xl||^2
__global__ __launch_bounds__(512)
void vq_prep(const float* __restrict__ X, const float* __restrict__ E,
             float* __restrict__ ET, float* __restrict__ normE,
             char* __restrict__ Es, char* __restrict__ Xs,
             float* __restrict__ xlnorm2, u32* __restrict__ maxe) {
    __shared__ float tile[64][65];
    __shared__ float mred[512];
    const int bid = blockIdx.x;
    const int t = threadIdx.x;
    if (bid < 64) {
        const int j0 = (bid & 15) * 64, d0 = (bid >> 4) * 64;
        const int tj = t & 63, td = t >> 6;
#pragma unroll
        for (int k = 0; k < 8; k++) {
            int dl = k * 8 + td;
            tile[dl][tj] = E[(d0 + dl) * NUM_EMB + j0 + tj];
        }
        __syncthreads();
        const int dd = t & 63, tw = t >> 6;
#pragma unroll
        for (int k = 0; k < 8; k++) {
            int jj = k * 8 + tw;
            ET[(j0 + jj) * EMB_DIM + d0 + dd] = tile[dd][jj];
        }
    } else if (bid < 66) {
        const int j = (bid - 64) * 512 + t;
        float s = 0.f;
#pragma unroll 8
        for (int d = 0; d < EMB_DIM; d++) {
            float v = E[d * NUM_EMB + j];
            s = fmaf(v, v, s);
        }
        normE[j] = s;
        mred[t] = s;
        __syncthreads();
        for (int k = 256; k > 0; k >>= 1) {
            if (t < k) mred[t] = fmaxf(mred[t], mred[t + k]);
            __syncthreads();
        }
        if (t == 0) atomicMax(maxe, __float_as_uint(mred[0]));   // positive floats: u32-monotone
    } else if (bid < 98) {
        const int rb = bid - 66;                // 0..31
        const int nblk = rb >> 3, ks = rb & 7;
#pragma unroll
        for (int i = 0; i < 4; i++) {
            int gid = i * 512 + t;              // 256 cols x 8 k8-groups
            int col = gid >> 3;
            int k8 = gid & 7;
            int kg = ks * 64 + k8 * 8;
            int isLo = kg >= 256;
            int d0 = isLo ? kg - 256 : kg;
            int colg = nblk * 256 + col;
            short8v v;
#pragma unroll
            for (int j = 0; j < 8; j++) {
                float e = E[(d0 + j) * NUM_EMB + colg];
                unsigned short h = f2bf(e);
                if (isLo) h = f2bf(e - bf2f(h));
                v[j] = (short)h;
            }
            size_t off = (size_t)nblk * 262144 + (size_t)ks * 32768 +
                         (size_t)(((col * 128 + (k8 * 8) * 2) ^ ((col & 7) << 4)));
            *(short8v*)(Es + off) = v;
        }
    } else {
        const int pb = bid - 98;                // 0..255
        const int mblk = pb >> 1;               // 0..127 (256-row tiles)
        const int rhalf = (pb & 1) * 128;
#pragma unroll
        for (int i = 0; i < 8; i++) {
            int gid = i * 512 + t;              // 128 rows x 32 d8-groups
            int row = rhalf + (gid >> 5);       // 0..255
            int d0 = (gid & 31) * 8;
            const float4* xp4 = (const float4*)(X + ((size_t)mblk * 256 + row) * 256 + d0);
            float4 xa = xp4[0], xb = xp4[1];
            float xv[8] = {xa.x, xa.y, xa.z, xa.w, xb.x, xb.y, xb.z, xb.w};
            short8v vh;
            float sl = 0.f;
#pragma unroll
            for (int j = 0; j < 8; j++) {
                unsigned short h = f2bf(xv[j]);
                vh[j] = (short)h;
                float xl = xv[j] - bf2f(h);     // exact residual
                sl = fmaf(xl, xl, sl);
            }
            int ksh = d0 >> 6, kl = d0 & 63;
            size_t inner = (size_t)(((row * 128 + kl * 2) ^ ((row & 7) << 4)));
            size_t base = (size_t)mblk * 262144;
            *(short8v*)(Xs + base + (size_t)ksh * 32768 + inner) = vh;
            // per-row ||xl||^2: 32 consecutive lanes own a row (gid&31 == t&31)
#pragma unroll
            for (int off = 16; off; off >>= 1) sl += __shfl_xor(sl, off, 64);
            if ((t & 31) == 0) xlnorm2[mblk * 256 + row] = sl;
        }
    }
}

// ---- GEMM + per-block argmin/second-best: r10 structure, K=512 (2 panels) ----
// grid 512 = 128 mblk x 4 nblk (XCD swizzle); 512 thr (8 waves 2x4, wave tile 128x64)
// BM=256 BN=256 BK=64; LDS 128KB = 2 bufs x (A 32K + B 32K); 8 K-steps
// D = Xh*Eh + Xh*El = Xh*E; A ksteps {0,1,2,3,0,1,2,3}; B ksteps {0..7}
// staging front-loaded: p0 = all 4 A-GLLs of tile s+1, p1 = all 4 B-GLLs; drain end of p3
__global__ __launch_bounds__(512, 1)
void vq_gemm(const char* __restrict__ Xs, const char* __restrict__ Es,
             const float* __restrict__ normE,
             u64* __restrict__ gkey, float* __restrict__ gm2) {
    extern __shared__ char smem[];
    const int t = threadIdx.x;
    const int bid = blockIdx.x;
    const int lbid = (bid & 7) * 64 + (bid >> 3);   // bijective: 512 = 8 XCD x 64
    const int mblk = lbid >> 2;
    const int nblk = lbid & 3;
    const int w = t >> 6, l = t & 63;
    const int wm = w >> 2, wn = w & 3;              // 2 x 4 wave grid
    const int lr = l & 15, lg = l >> 4;
    const int swz = (l & 7) << 4;

    const char* Asrc = Xs + (size_t)mblk * 262144;
    const char* Bsrc = Es + (size_t)nblk * 262144;

    const int aBase = (wm * 128 + lr) * 128;
    const int bBase = (wn * 64 + lr) * 128;
    const int c0off = (lg * 16) ^ swz;
    const int c1off = (64 + lg * 16) ^ swz;

    f32x4 acc[8][4];
#pragma unroll
    for (int mt = 0; mt < 8; mt++)
#pragma unroll
        for (int nt = 0; nt < 4; nt++) acc[mt][nt] = (f32x4){0.f, 0.f, 0.f, 0.f};

#define GLL(srcp, dstoff) __builtin_amdgcn_global_load_lds(GLP(srcp), LDSP(smem + (dstoff)), 16, 0, 0)
#define BARRIER() { asm volatile("" ::: "memory"); __builtin_amdgcn_s_barrier(); asm volatile("" ::: "memory"); }
#define LGKM0() { asm volatile("s_waitcnt lgkmcnt(0)" ::: "memory"); __builtin_amdgcn_sched_barrier(0); }

    // prologue: stage tile 0 -> buf 0, drain
    {
#pragma unroll
        for (int q = 0; q < 4; q++) GLL(Asrc + q * 8192 + t * 16, q * 8192 + t * 16);
#pragma unroll
        for (int q = 0; q < 4; q++) GLL(Bsrc + q * 8192 + t * 16, 32768 + q * 8192 + t * 16);
        asm volatile("s_waitcnt vmcnt(0)" ::: "memory");
        BARRIER();
    }

    const int AK[8] = {0, 1, 2, 3, 0, 1, 2, 3};
    const int BK[8] = {0, 1, 2, 3, 4, 5, 6, 7};

#pragma unroll
    for (int s = 0; s < 8; s++) {
        const int buf = s & 1, nbuf = buf ^ 1;
        const char* Ab = smem + buf * 65536;
        const char* Bb = Ab + 32768;
        const int And = nbuf * 65536;
        const int Bnd = And + 32768;
        const char* aN = Asrc + (s < 7 ? AK[s + 1] : 0) * 32768;
        const char* bN = Bsrc + (s < 7 ? BK[s + 1] : 0) * 32768;

        short8v af[4], bf[4];

        // ---- phase 0: kk0, mt 0-3 (+ B kk0); stage all 4 A-GLLs of tile s+1
#pragma unroll
        for (int mt = 0; mt < 4; mt++) af[mt] = *(const short8v*)(Ab + aBase + mt * 2048 + c0off);
#pragma unroll
        for (int nt = 0; nt < 4; nt++) bf[nt] = *(const short8v*)(Bb + bBase + nt * 2048 + c0off);
        if (s < 7) {
            GLL(aN + t * 16, And + t * 16);
            GLL(aN + 8192 + t * 16, And + 8192 + t * 16);
            GLL(aN + 16384 + t * 16, And + 16384 + t * 16);
            GLL(aN + 24576 + t * 16, And + 24576 + t * 16);
        }
        BARRIER();
        LGKM0();
        __builtin_amdgcn_s_setprio(1);
#pragma unroll
        for (int mt = 0; mt < 4; mt++)
#pragma unroll
            for (int nt = 0; nt < 4; nt++)
                acc[mt][nt] = __builtin_amdgcn_mfma_f32_16x16x32_bf16(af[mt], bf[nt], acc[mt][nt], 0, 0, 0);
        __builtin_amdgcn_s_setprio(0);
        BARRIER();

        // ---- phase 1: kk0, mt 4-7 (B kk0 kept); stage all 4 B-GLLs of tile s+1
#pragma unroll
        for (int mt = 0; mt < 4; mt++) af[mt] = *(const short8v*)(Ab + aBase + (mt + 4) * 2048 + c0off);
        if (s < 7) {
            GLL(bN + t * 16, Bnd + t * 16);
            GLL(bN + 8192 + t * 16, Bnd + 8192 + t * 16);
            GLL(bN + 16384 + t * 16, Bnd + 16384 + t * 16);
            GLL(bN + 24576 + t * 16, Bnd + 24576 + t * 16);
        }
        BARRIER();
        LGKM0();
        __builtin_amdgcn_s_setprio(1);
#pragma unroll
        for (int mt = 0; mt < 4; mt++)
#pragma unroll
            for (int nt = 0; nt < 4; nt++)
                acc[mt + 4][nt] = __builtin_amdgcn_mfma_f32_16x16x32_bf16(af[mt], bf[nt], acc[mt + 4][nt], 0, 0, 0);
        __builtin_amdgcn_s_setprio(0);
        BARRIER();

        // ---- phase 2: kk1, mt 0-3 (+ B kk1)
#pragma unroll
        for (int mt = 0; mt < 4; mt++) af[mt] = *(const short8v*)(Ab + aBase + mt * 2048 + c1off);
#pragma unroll
        for (int nt = 0; nt < 4; nt++) bf[nt] = *(const short8v*)(Bb + bBase + nt * 2048 + c1off);
        BARRIER();
        LGKM0();
        __builtin_amdgcn_s_setprio(1);
#pragma unroll
        for (int mt = 0; mt < 4; mt++)
#pragma unroll
            for (int nt = 0; nt < 4; nt++)
                acc[mt][nt] = __builtin_amdgcn_mfma_f32_16x16x32_bf16(af[mt], bf[nt], acc[mt][nt], 0, 0, 0);
        __builtin_amdgcn_s_setprio(0);
        BARRIER();

        // ---- phase 3: kk1, mt 4-7; drain (loads are ~3 phases old -> cheap)
#pragma unroll
        for (int mt = 0; mt < 4; mt++) af[mt] = *(const short8v*)(Ab + aBase + (mt + 4) * 2048 + c1off);
        BARRIER();
        LGKM0();
        __builtin_amdgcn_s_setprio(1);
#pragma unroll
        for (int mt = 0; mt < 4; mt++)
#pragma unroll
            for (int nt = 0; nt < 4; nt++)
                acc[mt + 4][nt] = __builtin_amdgcn_mfma_f32_16x16x32_bf16(af[mt], bf[nt], acc[mt + 4][nt], 0, 0, 0);
        __builtin_amdgcn_s_setprio(0);
        if (s < 7) asm volatile("s_waitcnt vmcnt(0)" ::: "memory");
        BARRIER();
    }
#undef GLL

    // epilogue: per-lane argmin over nt, 16-lane reduce, cross-wn via LDS; track second-best
    float ne_v[4];
#pragma unroll
    for (int nt = 0; nt < 4; nt++) ne_v[nt] = normE[nblk * 256 + wn * 64 + nt * 16 + lr];

#pragma unroll
    for (int mt = 0; mt < 8; mt++) {
#pragma unroll
        for (int r = 0; r < 4; r++) {
            float m1 = __uint_as_float(0x7F7FFFFFu);   // FLT_MAX
            float m2 = m1;
            u32 col = 0;
#pragma unroll
            for (int nt = 0; nt < 4; nt++) {
                float f = fmaf(-2.0f, acc[mt][nt][r], ne_v[nt]);
                float mx = fmaxf(m1, f);
                m2 = fminf(m2, mx);
                bool p = f < m1;
                m1 = fminf(m1, f);
                u32 cg = (u32)(nblk * 256 + wn * 64 + nt * 16 + lr);
                col = p ? cg : col;
            }
            u64 key = ((u64)sortable(m1) << 32) | col;
#pragma unroll
            for (int off = 1; off < 16; off <<= 1) {
                u64 ko = __shfl_xor(key, off, 16);
                float m1o = __shfl_xor(m1, off, 16);
                float m2o = __shfl_xor(m2, off, 16);
                m2 = fminf(fminf(m2, m2o), fmaxf(m1, m1o));
                m1 = fminf(m1, m1o);
                key = umin64(key, ko);
            }
            if (lr == 0) {
                int slot = (wm * 128 + mt * 16 + lg * 4 + r) * 4 + wn;
                *(u64*)(smem + slot * 16) = key;
                *(float*)(smem + slot * 16 + 8) = m2;
            }
        }
    }
    __syncthreads();
    if (t < 256) {
        u64 k_i[4]; float m2_i[4];
#pragma unroll
        for (int i = 0; i < 4; i++) {
            k_i[i] = *(const u64*)(smem + (t * 4 + i) * 16);
            m2_i[i] = *(const float*)(smem + (t * 4 + i) * 16 + 8);
        }
        u64 K = umin64(umin64(k_i[0], k_i[1]), umin64(k_i[2], k_i[3]));
        float F2 = __uint_as_float(0x7F7FFFFFu);
#pragma unroll
        for (int i = 0; i < 4; i++) {
            float f1i = unsortable((u32)(k_i[i] >> 32));
            F2 = fminf(F2, (k_i[i] == K) ? m2_i[i] : f1i);
        }
        int rowg = mblk * 256 + t;
        gkey[(size_t)nblk * 32768 + rowg] = K;
        gm2[(size_t)nblk * 32768 + rowg] = F2;
    }
}

// ---- combine 4 nblk results -> idx + flag list (per-row deterministic margin) ----
// |gemm_dist - exact_dist| per col <= 2*(||xl||*maxE + eps). Safe margin = 4*||xl||*maxE + 4e-4.
__global__ __launch_bounds__(512) void vq_combine(const u64* __restrict__ gkey, const float* __restrict__ gm2,
                                                  const float* __restrict__ xlnorm2, const u32* __restrict__ maxe,
                                                  u32* __restrict__ idx_arr, u32* __restrict__ flaglist,
                                                  u32* __restrict__ cnt) {
    const int row = blockIdx.x * 512 + threadIdx.x;
    u64 k_i[4]; float m2_i[4];
#pragma unroll
    for (int n = 0; n < 4; n++) {
        k_i[n] = gkey[(size_t)n * 32768 + row];
        m2_i[n] = gm2[(size_t)n * 32768 + row];
    }
    u64 K = umin64(umin64(k_i[0], k_i[1]), umin64(k_i[2], k_i[3]));
    float F1 = unsortable((u32)(K >> 32));
    float F2 = __uint_as_float(0x7F7FFFFFu);
#pragma unroll
    for (int n = 0; n < 4; n++) {
        float f1i = unsortable((u32)(k_i[n] >> 32));
        F2 = fminf(F2, (k_i[n] == K) ? m2_i[n] : f1i);
    }
    idx_arr[row] = (u32)(K & 0xFFFFFFFFu);
    const float maxE = sqrtf(__uint_as_float(*maxe));
    const float margin = 4.0f * sqrtf(xlnorm2[row]) * maxE + 4e-4f;
    if (F2 - F1 < margin) {
        u32 p = atomicAdd(cnt, 1u);
        flaglist[p] = (u32)row;
    }
}

// ---- exact fp32 recheck, batched 4 rows/block (bit-identical per-row math to verified r2 path) ----
__global__ __launch_bounds__(512) void vq_recheck(const float* __restrict__ X, const float* __restrict__ E,
                                                  const float* __restrict__ normE,
                                                  const u32* __restrict__ flaglist, const u32* __restrict__ cnt,
                                                  u32* __restrict__ idx_arr) {
    __shared__ __align__(16) float xs4[4][256];
    __shared__ float r2part[4][32];
    __shared__ float r2s[4];
    __shared__ u64 wkey[4][8];
    const int t = threadIdx.x;
    const int n = (int)*cnt;
    const int nbatch = (n + 3) >> 2;
    for (int b = blockIdx.x; b < nbatch; b += 1024) {
        __syncthreads();
        const int rem = n - b * 4;
        const int nr = rem < 4 ? rem : 4;
        if (t < 256) {
            const int r = t >> 6, li = t & 63;
            if (r < nr) {
                const int row = (int)flaglist[b * 4 + r];
                ((float4*)xs4[r])[li] = ((const float4*)(X + (size_t)row * 256))[li];
            }
        }
        __syncthreads();
        if (t < 128) {
            const int r = t >> 5, l = t & 31;
            float s = 0.f;
#pragma unroll
            for (int k = 0; k < 8; k++) {
                float v = xs4[r][l * 8 + k];
                s = fmaf(v, v, s);
            }
            r2part[r][l] = s;
        }
        __syncthreads();
        if (t < 4) {
            float s = 0.f;
#pragma unroll
            for (int k = 0; k < 32; k++) s += r2part[t][k];
            r2s[t] = s;
        }
        __syncthreads();
        const int c0 = t * 2;
        float ax[4] = {0.f, 0.f, 0.f, 0.f}, ay[4] = {0.f, 0.f, 0.f, 0.f};
        for (int d = 0; d < 256; d += 4) {
            const float2 e0 = *(const float2*)(E + (d + 0) * NUM_EMB + c0);
            const float2 e1 = *(const float2*)(E + (d + 1) * NUM_EMB + c0);
            const float2 e2 = *(const float2*)(E + (d + 2) * NUM_EMB + c0);
            const float2 e3 = *(const float2*)(E + (d + 3) * NUM_EMB + c0);
#pragma unroll
            for (int r = 0; r < 4; r++) {
                const float4 xv = *(const float4*)(&xs4[r][d]);
                ax[r] = fmaf(xv.x, e0.x, ax[r]); ay[r] = fmaf(xv.x, e0.y, ay[r]);
                ax[r] = fmaf(xv.y, e1.x, ax[r]); ay[r] = fmaf(xv.y, e1.y, ay[r]);
                ax[r] = fmaf(xv.z, e2.x, ax[r]); ay[r] = fmaf(xv.z, e2.y, ay[r]);
                ax[r] = fmaf(xv.w, e3.x, ax[r]); ay[r] = fmaf(xv.w, e3.y, ay[r]);
            }
        }
        const float2 ne = *(const float2*)(normE + c0);
#pragma unroll
        for (int r = 0; r < 4; r++) {
            if (r < nr) {
                const float f0 = (r2s[r] + ne.x) - 2.0f * ax[r];
                const float f1 = (r2s[r] + ne.y) - 2.0f * ay[r];
                u64 k0 = ((u64)sortable(f0) << 32) | (u32)c0;
                u64 k1 = ((u64)sortable(f1) << 32) | (u32)(c0 + 1);
                u64 km = umin64(k0, k1);
#pragma unroll
                for (int off = 32; off; off >>= 1) km = umin64(km, __shfl_xor(km, off, 64));
                if ((t & 63) == 0) wkey[r][t >> 6] = km;
            }
        }
        __syncthreads();
        if (t < 4 && t < nr) {
            u64 m = wkey[t][0];
#pragma unroll
            for (int w2 = 1; w2 < 8; w2++) m = umin64(m, wkey[t][w2]);
            idx_arr[(int)flaglist[b * 4 + t]] = (u32)(m & 0xFFFFFFFFull);
        }
    }
}

// ---- straight-through out + loss partials ----
__global__ __launch_bounds__(512) void vq_out(const float* __restrict__ X, const float* __restrict__ ET,
                                              const u32* __restrict__ idx_arr,
                                              float* __restrict__ out, float* __restrict__ partial) {
    __shared__ float lred[8];
    const int t = threadIdx.x;
    const long long base = (long long)blockIdx.x * 4096;   // 16 rows * 256
    const int dcol = t & 255, half = t >> 8;
    float lsum = 0.f;
#pragma unroll
    for (int rr = 0; rr < 8; rr++) {
        const int r = half * 8 + rr;
        const int row = blockIdx.x * 16 + r;
        const u32 idx = idx_arr[row];
        const float q = ET[(size_t)idx * EMB_DIM + dcol];
        const float x = X[base + r * EMB_DIM + dcol];
        out[base + r * EMB_DIM + dcol] = x + (q - x);
        const float df = x - q;
        lsum = fmaf(df, df, lsum);
    }
#pragma unroll
    for (int off = 32; off; off >>= 1) lsum += __shfl_down(lsum, off, 64);
    if ((t & 63) == 0) lred[t >> 6] = lsum;
    __syncthreads();
    if (t == 0) {
        float s = 0.f;
#pragma unroll
        for (int w = 0; w < 8; w++) s += lred[w];
        partial[blockIdx.x] = s;
    }
}

// ---- finish: loss = m + 0.25*m ----
__global__ void vq_finish(const float* __restrict__ partial, float* __restrict__ loss_out) {
    __shared__ float red[256];
    const int t = threadIdx.x;
    float s = 0.f;
    for (int i = t; i < 2048; i += 256) s += partial[i];
    red[t] = s;
    __syncthreads();
    for (int k = 128; k > 0; k >>= 1) {
        if (t < k) red[t] += red[t + k];
        __syncthreads();
    }
    if (t == 0) {
        const float m = red[0] / 8388608.0f;
        loss_out[0] = fmaf(0.25f, m, m);
    }
}

extern "C" void kernel_launch(void* const* d_in, const int* in_sizes, int n_in,
                              void* d_out, int out_size, void* d_ws, size_t ws_size,
                              hipStream_t stream) {
    const float* X = (const float*)d_in[0];      // (32,32,32,256) fp32
    const float* E = (const float*)d_in[1];      // (256,1024) fp32
    float* out = (float*)d_out;

    // workspace layout (bytes)
    char* ws = (char*)d_ws;
    float* ET       = (float*)(ws + 0);            // 1 MB
    float* normE    = (float*)(ws + 1048576);      // 4 KB
    float* partial  = (float*)(ws + 1052672);      // 8 KB
    char*  Es       = ws + 1060864;                // 1 MB
    u64*   gkey     = (u64*)(ws + 2109440);        // 1 MB
    float* gm2      = (float*)(ws + 3158016);      // 512 KB
    u32*   idx_arr  = (u32*)(ws + 3682304);        // 128 KB
    u32*   flaglist = (u32*)(ws + 3813376);        // 128 KB
    u32*   cnt      = (u32*)(ws + 3944448);        // 4 B
    u32*   maxe     = (u32*)(ws + 3944452);        // 4 B
    float* xlnorm2  = (float*)(ws + 3944960);      // 128 KB

    // Xs (bf16 hi panel, 16 MB) aliases d_out; fully consumed before vq_out overwrites.
    char* Xs = (char*)d_out;

    hipMemsetAsync(cnt, 0, 8, stream);             // cnt + maxe
    vq_prep<<<354, 512, 0, stream>>>(X, E, ET, normE, Es, Xs, xlnorm2, maxe);
    vq_gemm<<<512, 512, 131072, stream>>>(Xs, Es, normE, gkey, gm2);
    vq_combine<<<64, 512, 0, stream>>>(gkey, gm2, xlnorm2, maxe, idx_arr, flaglist, cnt);
    vq_recheck<<<1024, 512, 0, stream>>>(X, E, normE, flaglist, cnt, idx_arr);
    vq_out<<<2048, 512, 0, stream>>>(X, ET, idx_arr, out, partial);
    vq_finish<<<1, 256, 0, stream>>>(partial, out + (out_size - 1));
}

// Round 13
// 129.661 us; speedup vs baseline: 1.5660x; 1.5660x over previous
//
#include <hip/hip_runtime.h>

#define NUM_EMB 1024
#define EMB_DIM 256

typedef __attribute__((ext_vector_type(8))) short short8v;
typedef _Float16 half8v __attribute__((ext_vector_type(8)));
typedef __attribute__((ext_vector_type(4))) float f32x4;
typedef unsigned long long u64;
typedef unsigned int u32;

__device__ __forceinline__ u32 sortable(float f) {
    u32 u = __float_as_uint(f);
    return (u & 0x80000000u) ? ~u : (u | 0x80000000u);
}
__device__ __forceinline__ float unsortable(u32 s) {
    u32 u = (s & 0x80000000u) ? (s & 0x7FFFFFFFu) : ~s;
    return __uint_as_float(u);
}
__device__ __forceinline__ u64 umin64(u64 a, u64 b) { return a < b ? a : b; }

// fp32 -> fp16 (RNE) bits and back
__device__ __forceinline__ unsigned short f2h_bits(float f) {
    _Float16 h = (_Float16)f;
    return *(unsigned short*)&h;
}
__device__ __forceinline__ float h2f(unsigned short b) {
    _Float16 h = *(_Float16*)&b;
    return (float)h;
}

#define GLP(p)  ((const __attribute__((address_space(1))) unsigned int*)(p))
#define LDSP(p) ((__attribute__((address_space(3))) unsigned int*)(p))

// ---- fused prep ----
// bid 0..63  : transpose E -> ET
// bid 64..65 : normE + atomicMax ||e||^2 (maxeh) + atomicMax ||el||^2 (maxel)
// bid 66..81 : eprep fp16 [nblk 4][ks 0..3][32KB swizzled]
// bid 82..337: xprep fp16 hi panel [mblk 128 of 256 rows][ks 0..3][32KB swizzled]
//              + per-row ||xh||^2, ||xl||^2   (xl = x - fp16(x), exact)
__global__ __launch_bounds__(512)
void vq_prep(const float* __restrict__ X, const float* __restrict__ E,
             float* __restrict__ ET, float* __restrict__ normE,
             char* __restrict__ Es, char* __restrict__ Xs,
             float* __restrict__ xl2arr, float* __restrict__ xh2arr,
             u32* __restrict__ maxeh, u32* __restrict__ maxel) {
    __shared__ float tile[64][65];
    __shared__ float mred[512];
    __shared__ float mred2[512];
    const int bid = blockIdx.x;
    const int t = threadIdx.x;
    if (bid < 64) {
        const int j0 = (bid & 15) * 64, d0 = (bid >> 4) * 64;
        const int tj = t & 63, td = t >> 6;
#pragma unroll
        for (int k = 0; k < 8; k++) {
            int dl = k * 8 + td;
            tile[dl][tj] = E[(d0 + dl) * NUM_EMB + j0 + tj];
        }
        __syncthreads();
        const int dd = t & 63, tw = t >> 6;
#pragma unroll
        for (int k = 0; k < 8; k++) {
            int jj = k * 8 + tw;
            ET[(j0 + jj) * EMB_DIM + d0 + dd] = tile[dd][jj];
        }
    } else if (bid < 66) {
        const int j = (bid - 64) * 512 + t;
        float s = 0.f, sel = 0.f;
#pragma unroll 8
        for (int d = 0; d < EMB_DIM; d++) {
            float v = E[d * NUM_EMB + j];
            s = fmaf(v, v, s);
            float el = v - h2f(f2h_bits(v));
            sel = fmaf(el, el, sel);
        }
        normE[j] = s;
        mred[t] = s;
        mred2[t] = sel;
        __syncthreads();
        for (int k = 256; k > 0; k >>= 1) {
            if (t < k) {
                mred[t] = fmaxf(mred[t], mred[t + k]);
                mred2[t] = fmaxf(mred2[t], mred2[t + k]);
            }
            __syncthreads();
        }
        if (t == 0) {
            atomicMax(maxeh, __float_as_uint(mred[0]));     // positive floats: u32-monotone
            atomicMax(maxel, __float_as_uint(mred2[0]));
        }
    } else if (bid < 82) {
        const int rb = bid - 66;                // 0..15
        const int nblk = rb >> 2, ks = rb & 3;
#pragma unroll
        for (int i = 0; i < 4; i++) {
            int gid = i * 512 + t;              // 256 cols x 8 k8-groups
            int col = gid >> 3;
            int k8 = gid & 7;
            int kg = ks * 64 + k8 * 8;          // [0,256)
            int colg = nblk * 256 + col;
            short8v v;
#pragma unroll
            for (int j = 0; j < 8; j++)
                v[j] = (short)f2h_bits(E[(kg + j) * NUM_EMB + colg]);
            size_t off = (size_t)nblk * 131072 + (size_t)ks * 32768 +
                         (size_t)(((col * 128 + (k8 * 8) * 2) ^ ((col & 7) << 4)));
            *(short8v*)(Es + off) = v;
        }
    } else {
        const int pb = bid - 82;                // 0..255
        const int mblk = pb >> 1;               // 0..127 (256-row tiles)
        const int rhalf = (pb & 1) * 128;
#pragma unroll
        for (int i = 0; i < 8; i++) {
            int gid = i * 512 + t;              // 128 rows x 32 d8-groups
            int row = rhalf + (gid >> 5);       // 0..255
            int d0 = (gid & 31) * 8;
            const float4* xp4 = (const float4*)(X + ((size_t)mblk * 256 + row) * 256 + d0);
            float4 xa = xp4[0], xb = xp4[1];
            float xv[8] = {xa.x, xa.y, xa.z, xa.w, xb.x, xb.y, xb.z, xb.w};
            short8v vh;
            float sl = 0.f, sh = 0.f;
#pragma unroll
            for (int j = 0; j < 8; j++) {
                unsigned short hb = f2h_bits(xv[j]);
                vh[j] = (short)hb;
                float hf = h2f(hb);
                float xl = xv[j] - hf;          // exact residual
                sl = fmaf(xl, xl, sl);
                sh = fmaf(hf, hf, sh);
            }
            int ksh = d0 >> 6, kl = d0 & 63;
            size_t inner = (size_t)(((row * 128 + kl * 2) ^ ((row & 7) << 4)));
            size_t base = (size_t)mblk * 131072;
            *(short8v*)(Xs + base + (size_t)ksh * 32768 + inner) = vh;
#pragma unroll
            for (int off = 16; off; off >>= 1) {
                sl += __shfl_xor(sl, off, 64);
                sh += __shfl_xor(sh, off, 64);
            }
            if ((t & 31) == 0) {
                xl2arr[mblk * 256 + row] = sl;
                xh2arr[mblk * 256 + row] = sh;
            }
        }
    }
}

// ---- GEMM (fp16, K=256) + per-block argmin/second-best: r12-proven 4-phase structure ----
// grid 512 = 128 mblk x 4 nblk (XCD swizzle); 512 thr (8 waves 2x4, wave tile 128x64)
// BM=256 BN=256 BK=64; LDS 128KB = 2 bufs x (A 32K + B 32K); 4 K-steps
__global__ __launch_bounds__(512, 1)
void vq_gemm(const char* __restrict__ Xs, const char* __restrict__ Es,
             const float* __restrict__ normE,
             u64* __restrict__ gkey, float* __restrict__ gm2) {
    extern __shared__ char smem[];
    const int t = threadIdx.x;
    const int bid = blockIdx.x;
    const int lbid = (bid & 7) * 64 + (bid >> 3);   // bijective: 512 = 8 XCD x 64
    const int mblk = lbid >> 2;
    const int nblk = lbid & 3;
    const int w = t >> 6, l = t & 63;
    const int wm = w >> 2, wn = w & 3;
    const int lr = l & 15, lg = l >> 4;
    const int swz = (l & 7) << 4;

    const char* Asrc = Xs + (size_t)mblk * 131072;
    const char* Bsrc = Es + (size_t)nblk * 131072;

    const int aBase = (wm * 128 + lr) * 128;
    const int bBase = (wn * 64 + lr) * 128;
    const int c0off = (lg * 16) ^ swz;
    const int c1off = (64 + lg * 16) ^ swz;

    f32x4 acc[8][4];
#pragma unroll
    for (int mt = 0; mt < 8; mt++)
#pragma unroll
        for (int nt = 0; nt < 4; nt++) acc[mt][nt] = (f32x4){0.f, 0.f, 0.f, 0.f};

#define GLL(srcp, dstoff) __builtin_amdgcn_global_load_lds(GLP(srcp), LDSP(smem + (dstoff)), 16, 0, 0)
#define BARRIER() { asm volatile("" ::: "memory"); __builtin_amdgcn_s_barrier(); asm volatile("" ::: "memory"); }
#define LGKM0() { asm volatile("s_waitcnt lgkmcnt(0)" ::: "memory"); __builtin_amdgcn_sched_barrier(0); }

    // prologue: stage tile 0 -> buf 0, drain
    {
#pragma unroll
        for (int q = 0; q < 4; q++) GLL(Asrc + q * 8192 + t * 16, q * 8192 + t * 16);
#pragma unroll
        for (int q = 0; q < 4; q++) GLL(Bsrc + q * 8192 + t * 16, 32768 + q * 8192 + t * 16);
        asm volatile("s_waitcnt vmcnt(0)" ::: "memory");
        BARRIER();
    }

#pragma unroll
    for (int s = 0; s < 4; s++) {
        const int buf = s & 1, nbuf = buf ^ 1;
        const char* Ab = smem + buf * 65536;
        const char* Bb = Ab + 32768;
        const int And = nbuf * 65536;
        const int Bnd = And + 32768;
        const char* aN = Asrc + (s < 3 ? s + 1 : 0) * 32768;
        const char* bN = Bsrc + (s < 3 ? s + 1 : 0) * 32768;

        half8v af[4], bf[4];

        // ---- phase 0: kk0, mt 0-3 (+ B kk0); stage all 4 A-GLLs of tile s+1
#pragma unroll
        for (int mt = 0; mt < 4; mt++) af[mt] = *(const half8v*)(Ab + aBase + mt * 2048 + c0off);
#pragma unroll
        for (int nt = 0; nt < 4; nt++) bf[nt] = *(const half8v*)(Bb + bBase + nt * 2048 + c0off);
        if (s < 3) {
            GLL(aN + t * 16, And + t * 16);
            GLL(aN + 8192 + t * 16, And + 8192 + t * 16);
            GLL(aN + 16384 + t * 16, And + 16384 + t * 16);
            GLL(aN + 24576 + t * 16, And + 24576 + t * 16);
        }
        BARRIER();
        LGKM0();
        __builtin_amdgcn_s_setprio(1);
#pragma unroll
        for (int mt = 0; mt < 4; mt++)
#pragma unroll
            for (int nt = 0; nt < 4; nt++)
                acc[mt][nt] = __builtin_amdgcn_mfma_f32_16x16x32_f16(af[mt], bf[nt], acc[mt][nt], 0, 0, 0);
        __builtin_amdgcn_s_setprio(0);
        BARRIER();

        // ---- phase 1: kk0, mt 4-7 (B kk0 kept); stage all 4 B-GLLs of tile s+1
#pragma unroll
        for (int mt = 0; mt < 4; mt++) af[mt] = *(const half8v*)(Ab + aBase + (mt + 4) * 2048 + c0off);
        if (s < 3) {
            GLL(bN + t * 16, Bnd + t * 16);
            GLL(bN + 8192 + t * 16, Bnd + 8192 + t * 16);
            GLL(bN + 16384 + t * 16, Bnd + 16384 + t * 16);
            GLL(bN + 24576 + t * 16, Bnd + 24576 + t * 16);
        }
        BARRIER();
        LGKM0();
        __builtin_amdgcn_s_setprio(1);
#pragma unroll
        for (int mt = 0; mt < 4; mt++)
#pragma unroll
            for (int nt = 0; nt < 4; nt++)
                acc[mt + 4][nt] = __builtin_amdgcn_mfma_f32_16x16x32_f16(af[mt], bf[nt], acc[mt + 4][nt], 0, 0, 0);
        __builtin_amdgcn_s_setprio(0);
        BARRIER();

        // ---- phase 2: kk1, mt 0-3 (+ B kk1)
#pragma unroll
        for (int mt = 0; mt < 4; mt++) af[mt] = *(const half8v*)(Ab + aBase + mt * 2048 + c1off);
#pragma unroll
        for (int nt = 0; nt < 4; nt++) bf[nt] = *(const half8v*)(Bb + bBase + nt * 2048 + c1off);
        BARRIER();
        LGKM0();
        __builtin_amdgcn_s_setprio(1);
#pragma unroll
        for (int mt = 0; mt < 4; mt++)
#pragma unroll
            for (int nt = 0; nt < 4; nt++)
                acc[mt][nt] = __builtin_amdgcn_mfma_f32_16x16x32_f16(af[mt], bf[nt], acc[mt][nt], 0, 0, 0);
        __builtin_amdgcn_s_setprio(0);
        BARRIER();

        // ---- phase 3: kk1, mt 4-7; drain
#pragma unroll
        for (int mt = 0; mt < 4; mt++) af[mt] = *(const half8v*)(Ab + aBase + (mt + 4) * 2048 + c1off);
        BARRIER();
        LGKM0();
        __builtin_amdgcn_s_setprio(1);
#pragma unroll
        for (int mt = 0; mt < 4; mt++)
#pragma unroll
            for (int nt = 0; nt < 4; nt++)
                acc[mt + 4][nt] = __builtin_amdgcn_mfma_f32_16x16x32_f16(af[mt], bf[nt], acc[mt + 4][nt], 0, 0, 0);
        __builtin_amdgcn_s_setprio(0);
        if (s < 3) asm volatile("s_waitcnt vmcnt(0)" ::: "memory");
        BARRIER();
    }
#undef GLL

    // epilogue: per-lane argmin over nt, 16-lane reduce, cross-wn via LDS; track second-best
    float ne_v[4];
#pragma unroll
    for (int nt = 0; nt < 4; nt++) ne_v[nt] = normE[nblk * 256 + wn * 64 + nt * 16 + lr];

#pragma unroll
    for (int mt = 0; mt < 8; mt++) {
#pragma unroll
        for (int r = 0; r < 4; r++) {
            float m1 = __uint_as_float(0x7F7FFFFFu);   // FLT_MAX
            float m2 = m1;
            u32 col = 0;
#pragma unroll
            for (int nt = 0; nt < 4; nt++) {
                float f = fmaf(-2.0f, acc[mt][nt][r], ne_v[nt]);
                float mx = fmaxf(m1, f);
                m2 = fminf(m2, mx);
                bool p = f < m1;
                m1 = fminf(m1, f);
                u32 cg = (u32)(nblk * 256 + wn * 64 + nt * 16 + lr);
                col = p ? cg : col;
            }
            u64 key = ((u64)sortable(m1) << 32) | col;
#pragma unroll
            for (int off = 1; off < 16; off <<= 1) {
                u64 ko = __shfl_xor(key, off, 16);
                float m1o = __shfl_xor(m1, off, 16);
                float m2o = __shfl_xor(m2, off, 16);
                m2 = fminf(fminf(m2, m2o), fmaxf(m1, m1o));
                m1 = fminf(m1, m1o);
                key = umin64(key, ko);
            }
            if (lr == 0) {
                int slot = (wm * 128 + mt * 16 + lg * 4 + r) * 4 + wn;
                *(u64*)(smem + slot * 16) = key;
                *(float*)(smem + slot * 16 + 8) = m2;
            }
        }
    }
    __syncthreads();
    if (t < 256) {
        u64 k_i[4]; float m2_i[4];
#pragma unroll
        for (int i = 0; i < 4; i++) {
            k_i[i] = *(const u64*)(smem + (t * 4 + i) * 16);
            m2_i[i] = *(const float*)(smem + (t * 4 + i) * 16 + 8);
        }
        u64 K = umin64(umin64(k_i[0], k_i[1]), umin64(k_i[2], k_i[3]));
        float F2 = __uint_as_float(0x7F7FFFFFu);
#pragma unroll
        for (int i = 0; i < 4; i++) {
            float f1i = unsortable((u32)(k_i[i] >> 32));
            F2 = fminf(F2, (k_i[i] == K) ? m2_i[i] : f1i);
        }
        int rowg = mblk * 256 + t;
        gkey[(size_t)nblk * 32768 + rowg] = K;
        gm2[(size_t)nblk * 32768 + rowg] = F2;
    }
}

// ---- combine: per-row deterministic margin (fp16 panel) ----
// |dist_approx - dist_exact| per col <= 2*(||xh||*||el_j|| + ||xl||*||e_j||) + accum
// margin = 4*(||xh||*maxEL + ||xl||*maxEH) + 5e-4  (covers both cols + ref ulp grid)
__global__ __launch_bounds__(512) void vq_combine(const u64* __restrict__ gkey, const float* __restrict__ gm2,
                                                  const float* __restrict__ xl2arr, const float* __restrict__ xh2arr,
                                                  const u32* __restrict__ maxeh, const u32* __restrict__ maxel,
                                                  u32* __restrict__ idx_arr, u32* __restrict__ flaglist,
                                                  u32* __restrict__ cnt) {
    const int row = blockIdx.x * 512 + threadIdx.x;
    u64 k_i[4]; float m2_i[4];
#pragma unroll
    for (int n = 0; n < 4; n++) {
        k_i[n] = gkey[(size_t)n * 32768 + row];
        m2_i[n] = gm2[(size_t)n * 32768 + row];
    }
    u64 K = umin64(umin64(k_i[0], k_i[1]), umin64(k_i[2], k_i[3]));
    float F1 = unsortable((u32)(K >> 32));
    float F2 = __uint_as_float(0x7F7FFFFFu);
#pragma unroll
    for (int n = 0; n < 4; n++) {
        float f1i = unsortable((u32)(k_i[n] >> 32));
        F2 = fminf(F2, (k_i[n] == K) ? m2_i[n] : f1i);
    }
    idx_arr[row] = (u32)(K & 0xFFFFFFFFu);
    const float mEH = sqrtf(__uint_as_float(*maxeh));
    const float mEL = sqrtf(__uint_as_float(*maxel));
    const float margin = 4.0f * (sqrtf(xh2arr[row]) * mEL + sqrtf(xl2arr[row]) * mEH) + 5e-4f;
    if (F2 - F1 < margin) {
        u32 p = atomicAdd(cnt, 1u);
        flaglist[p] = (u32)row;
    }
}

// ---- exact fp32 recheck, batched 4 rows/block (r12-verified; bit-identical per-row math to r2) ----
__global__ __launch_bounds__(512) void vq_recheck(const float* __restrict__ X, const float* __restrict__ E,
                                                  const float* __restrict__ normE,
                                                  const u32* __restrict__ flaglist, const u32* __restrict__ cnt,
                                                  u32* __restrict__ idx_arr) {
    __shared__ __align__(16) float xs4[4][256];
    __shared__ float r2part[4][32];
    __shared__ float r2s[4];
    __shared__ u64 wkey[4][8];
    const int t = threadIdx.x;
    const int n = (int)*cnt;
    const int nbatch = (n + 3) >> 2;
    for (int b = blockIdx.x; b < nbatch; b += 1024) {
        __syncthreads();
        const int rem = n - b * 4;
        const int nr = rem < 4 ? rem : 4;
        if (t < 256) {
            const int r = t >> 6, li = t & 63;
            if (r < nr) {
                const int row = (int)flaglist[b * 4 + r];
                ((float4*)xs4[r])[li] = ((const float4*)(X + (size_t)row * 256))[li];
            }
        }
        __syncthreads();
        if (t < 128) {
            const int r = t >> 5, l = t & 31;
            float s = 0.f;
#pragma unroll
            for (int k = 0; k < 8; k++) {
                float v = xs4[r][l * 8 + k];
                s = fmaf(v, v, s);
            }
            r2part[r][l] = s;
        }
        __syncthreads();
        if (t < 4) {
            float s = 0.f;
#pragma unroll
            for (int k = 0; k < 32; k++) s += r2part[t][k];
            r2s[t] = s;
        }
        __syncthreads();
        const int c0 = t * 2;
        float ax[4] = {0.f, 0.f, 0.f, 0.f}, ay[4] = {0.f, 0.f, 0.f, 0.f};
        for (int d = 0; d < 256; d += 4) {
            const float2 e0 = *(const float2*)(E + (d + 0) * NUM_EMB + c0);
            const float2 e1 = *(const float2*)(E + (d + 1) * NUM_EMB + c0);
            const float2 e2 = *(const float2*)(E + (d + 2) * NUM_EMB + c0);
            const float2 e3 = *(const float2*)(E + (d + 3) * NUM_EMB + c0);
#pragma unroll
            for (int r = 0; r < 4; r++) {
                const float4 xv = *(const float4*)(&xs4[r][d]);
                ax[r] = fmaf(xv.x, e0.x, ax[r]); ay[r] = fmaf(xv.x, e0.y, ay[r]);
                ax[r] = fmaf(xv.y, e1.x, ax[r]); ay[r] = fmaf(xv.y, e1.y, ay[r]);
                ax[r] = fmaf(xv.z, e2.x, ax[r]); ay[r] = fmaf(xv.z, e2.y, ay[r]);
                ax[r] = fmaf(xv.w, e3.x, ax[r]); ay[r] = fmaf(xv.w, e3.y, ay[r]);
            }
        }
        const float2 ne = *(const float2*)(normE + c0);
#pragma unroll
        for (int r = 0; r < 4; r++) {
            if (r < nr) {
                const float f0 = (r2s[r] + ne.x) - 2.0f * ax[r];
                const float f1 = (r2s[r] + ne.y) - 2.0f * ay[r];
                u64 k0 = ((u64)sortable(f0) << 32) | (u32)c0;
                u64 k1 = ((u64)sortable(f1) << 32) | (u32)(c0 + 1);
                u64 km = umin64(k0, k1);
#pragma unroll
                for (int off = 32; off; off >>= 1) km = umin64(km, __shfl_xor(km, off, 64));
                if ((t & 63) == 0) wkey[r][t >> 6] = km;
            }
        }
        __syncthreads();
        if (t < 4 && t < nr) {
            u64 m = wkey[t][0];
#pragma unroll
            for (int w2 = 1; w2 < 8; w2++) m = umin64(m, wkey[t][w2]);
            idx_arr[(int)flaglist[b * 4 + t]] = (u32)(m & 0xFFFFFFFFull);
        }
    }
}

// ---- straight-through out + loss partials ----
__global__ __launch_bounds__(512) void vq_out(const float* __restrict__ X, const float* __restrict__ ET,
                                              const u32* __restrict__ idx_arr,
                                              float* __restrict__ out, float* __restrict__ partial) {
    __shared__ float lred[8];
    const int t = threadIdx.x;
    const long long base = (long long)blockIdx.x * 4096;   // 16 rows * 256
    const int dcol = t & 255, half = t >> 8;
    float lsum = 0.f;
#pragma unroll
    for (int rr = 0; rr < 8; rr++) {
        const int r = half * 8 + rr;
        const int row = blockIdx.x * 16 + r;
        const u32 idx = idx_arr[row];
        const float q = ET[(size_t)idx * EMB_DIM + dcol];
        const float x = X[base + r * EMB_DIM + dcol];
        out[base + r * EMB_DIM + dcol] = x + (q - x);
        const float df = x - q;
        lsum = fmaf(df, df, lsum);
    }
#pragma unroll
    for (int off = 32; off; off >>= 1) lsum += __shfl_down(lsum, off, 64);
    if ((t & 63) == 0) lred[t >> 6] = lsum;
    __syncthreads();
    if (t == 0) {
        float s = 0.f;
#pragma unroll
        for (int w = 0; w < 8; w++) s += lred[w];
        partial[blockIdx.x] = s;
    }
}

// ---- finish: loss = m + 0.25*m ----
__global__ void vq_finish(const float* __restrict__ partial, float* __restrict__ loss_out) {
    __shared__ float red[256];
    const int t = threadIdx.x;
    float s = 0.f;
    for (int i = t; i < 2048; i += 256) s += partial[i];
    red[t] = s;
    __syncthreads();
    for (int k = 128; k > 0; k >>= 1) {
        if (t < k) red[t] += red[t + k];
        __syncthreads();
    }
    if (t == 0) {
        const float m = red[0] / 8388608.0f;
        loss_out[0] = fmaf(0.25f, m, m);
    }
}

extern "C" void kernel_launch(void* const* d_in, const int* in_sizes, int n_in,
                              void* d_out, int out_size, void* d_ws, size_t ws_size,
                              hipStream_t stream) {
    const float* X = (const float*)d_in[0];      // (32,32,32,256) fp32
    const float* E = (const float*)d_in[1];      // (256,1024) fp32
    float* out = (float*)d_out;

    // workspace layout (bytes) — within the r12-proven extent
    char* ws = (char*)d_ws;
    float* ET       = (float*)(ws + 0);            // 1 MB
    float* normE    = (float*)(ws + 1048576);      // 4 KB
    float* partial  = (float*)(ws + 1052672);      // 8 KB
    char*  Es       = ws + 1060864;                // 512 KB (fp16, 4 nblk x 128KB)
    u64*   gkey     = (u64*)(ws + 2109440);        // 1 MB
    float* gm2      = (float*)(ws + 3158016);      // 512 KB
    u32*   idx_arr  = (u32*)(ws + 3682304);        // 128 KB
    u32*   flaglist = (u32*)(ws + 3813376);        // 128 KB
    u32*   cnt      = (u32*)(ws + 3944448);        // 4 B
    u32*   maxeh    = (u32*)(ws + 3944452);        // 4 B
    u32*   maxel    = (u32*)(ws + 3944456);        // 4 B

    // d_out upper region scratch: Xs fp16 panel (16 MB) + per-row norms (2 x 128 KB).
    // All consumed before vq_out overwrites d_out.
    char*  Xs      = (char*)d_out;
    float* xl2arr  = (float*)((char*)d_out + 16777216);
    float* xh2arr  = (float*)((char*)d_out + 16777216 + 131072);

    hipMemsetAsync(cnt, 0, 12, stream);            // cnt + maxeh + maxel
    vq_prep<<<338, 512, 0, stream>>>(X, E, ET, normE, Es, Xs, xl2arr, xh2arr, maxeh, maxel);
    vq_gemm<<<512, 512, 131072, stream>>>(Xs, Es, normE, gkey, gm2);
    vq_combine<<<64, 512, 0, stream>>>(gkey, gm2, xl2arr, xh2arr, maxeh, maxel, idx_arr, flaglist, cnt);
    vq_recheck<<<1024, 512, 0, stream>>>(X, E, normE, flaglist, cnt, idx_arr);
    vq_out<<<2048, 512, 0, stream>>>(X, ET, idx_arr, out, partial);
    vq_finish<<<1, 256, 0, stream>>>(partial, out + (out_size - 1));
}